// Round 4
// baseline (862.443 us; speedup 1.0000x reference)
//
#include <hip/hip_runtime.h>
#include <hip/hip_bf16.h>

#define DEPTH   6
#define DIM     192
#define HEADS   12
#define DH      16
#define MLPD    768
#define SEQ     256
#define BATCH   32
#define ROWS    (BATCH*SEQ)   // 8192

typedef __attribute__((ext_vector_type(8))) short short8;
typedef __attribute__((ext_vector_type(4))) float f32x4;
typedef __attribute__((ext_vector_type(4))) _Float16 half4;
typedef __hip_bfloat16 bf16_t;
typedef _Float16 f16_t;

__device__ __forceinline__ float b2f(bf16_t v){ return __bfloat162float(v); }
__device__ __forceinline__ bf16_t f2b(float v){ return __float2bfloat16(v); }
__device__ __forceinline__ ushort f2u(float v){
    union{ bf16_t b; ushort u; } w; w.b = __float2bfloat16(v); return w.u;
}
__device__ __forceinline__ f16_t u2h(ushort u){ union{ ushort u; f16_t h; } w; w.u = u; return w.h; }
__device__ __forceinline__ ushort h2u(f16_t h){ union{ ushort u; f16_t h; } w; w.h = h; return w.u; }

// async global->LDS, 16B per lane. LDS dest must be wave-uniform base + lane*16.
__device__ __forceinline__ void async16(ushort* lds, const ushort* gp){
    __builtin_amdgcn_global_load_lds(
        (const __attribute__((address_space(1))) uint*)gp,
        (__attribute__((address_space(3))) uint*)lds, 16, 0, 0);
}

// ---------------- residual init ----------------
__global__ void copy_kernel(const float* __restrict__ x, float* __restrict__ xr, int n){
    int i = blockIdx.x*256 + threadIdx.x;
    if (i < n) xr[i] = x[i];
}

// ---------------- weight transpose-convert: W[l][K][N] fp32 -> WT[l][N][K] bf16 ----
__global__ __launch_bounds__(256) void wt_kernel(const float* __restrict__ W,
        ushort* __restrict__ WT, int K, int N){
    __shared__ ushort T[64*72];
    int l = blockIdx.z;
    const float* src = W + ((size_t)l*K + blockIdx.x*64)*N + blockIdx.y*64;
    ushort* dst = WT + ((size_t)l*N + blockIdx.y*64)*K + blockIdx.x*64;
    int tid = threadIdx.x;
    int r = tid >> 2, c4 = (tid & 3)*16;     // read: row k=r, 16 n's
    #pragma unroll
    for (int u=0; u<4; u++){
        float4 v = *(const float4*)(src + (size_t)r*N + c4 + u*4);
        T[(c4+u*4+0)*72 + r] = f2u(v.x);
        T[(c4+u*4+1)*72 + r] = f2u(v.y);
        T[(c4+u*4+2)*72 + r] = f2u(v.z);
        T[(c4+u*4+3)*72 + r] = f2u(v.w);
    }
    __syncthreads();
    int n = tid >> 2, k8 = (tid & 3)*16;     // write: row n, 16 k's
    #pragma unroll
    for (int u=0; u<2; u++)
        *(uint4*)(dst + (size_t)n*K + k8 + u*8) = *(uint4*)&T[n*72 + k8 + u*8];
}

// ---------------- fused LN + GEMM (K = DIM = 192, single-shot) ----------------
// MODE 0: QKV — out cols <192 -> out0 (f16, stride 192), else out1 (f16, stride 384)
// MODE 1: W1  — z = acc+bias, exact GELU, store bf16 to out0 (stride MLPD)
template<int MODE>
__global__ __launch_bounds__(256) void gemm_ln_kernel(
        const float* __restrict__ xres, const float* __restrict__ ln_g,
        const float* __restrict__ ln_b, const ushort* __restrict__ BT0,
        const ushort* __restrict__ BT1, const float* __restrict__ bias,
        f16_t* __restrict__ out0, f16_t* __restrict__ out1){
    __shared__ ushort As[64*200];    // LN'd A rows, stride 200 (2-way banks)
    __shared__ ushort Bs[6*2048];    // full-K B tiles, async-staged
    int tid = threadIdx.x, lane = tid & 63, w = tid >> 6;
    int bm = blockIdx.x*64, bn = blockIdx.y*64;
    // issue all 6 B k-tile asyncs up front (overlap HBM with LN compute)
    {
        const ushort* bt; int bnl;
        if (MODE == 0 && bn >= DIM){ bt = BT1; bnl = bn - DIM; }
        else { bt = BT0; bnl = bn; }
        const ushort* bp = bt + (size_t)(bnl + (tid>>2))*DIM + (tid&3)*8;
        #pragma unroll
        for (int c=0; c<6; c++)
            async16(&Bs[c*2048 + tid*8], bp + c*32);
    }
    // LN prologue: 16 rows per wave, wave-per-row reduction
    float g0 = ln_g[lane], g1 = ln_g[lane+64], g2 = ln_g[lane+128];
    float e0 = ln_b[lane], e1 = ln_b[lane+64], e2 = ln_b[lane+128];
    for (int it = 0; it < 16; it++){
        int r = (w<<4) + it;
        const float* xr = xres + (size_t)(bm + r)*DIM;
        float v0 = xr[lane], v1 = xr[lane+64], v2 = xr[lane+128];
        float s = v0+v1+v2;
        #pragma unroll
        for (int off=32; off; off>>=1) s += __shfl_xor(s, off, 64);
        float m = s*(1.0f/192.0f);
        float d0=v0-m, d1=v1-m, d2=v2-m;
        float q = d0*d0+d1*d1+d2*d2;
        #pragma unroll
        for (int off=32; off; off>>=1) q += __shfl_xor(q, off, 64);
        float inv = rsqrtf(q*(1.0f/192.0f) + 1e-5f);
        ushort* dst = &As[r*200];
        dst[lane]     = f2u(d0*inv*g0 + e0);
        dst[lane+64]  = f2u(d1*inv*g1 + e1);
        dst[lane+128] = f2u(d2*inv*g2 + e2);
    }
    __syncthreads();   // drains asyncs (vmcnt) + As visible
    int wrow = w >> 1, wcol = w & 1;
    int quad = lane >> 4, mr = lane & 15;
    f32x4 acc[2][2] = {};
    #pragma unroll
    for (int c = 0; c < 6; c++){
        short8 a0 = *(const short8*)&As[(wrow*32+mr)*200    + c*32 + quad*8];
        short8 a1 = *(const short8*)&As[(wrow*32+16+mr)*200 + c*32 + quad*8];
        short8 b0 = *(const short8*)&Bs[c*2048 + (wcol*32+mr)*32    + quad*8];
        short8 b1 = *(const short8*)&Bs[c*2048 + (wcol*32+16+mr)*32 + quad*8];
        acc[0][0] = __builtin_amdgcn_mfma_f32_16x16x32_bf16(a0, b0, acc[0][0], 0,0,0);
        acc[0][1] = __builtin_amdgcn_mfma_f32_16x16x32_bf16(a0, b1, acc[0][1], 0,0,0);
        acc[1][0] = __builtin_amdgcn_mfma_f32_16x16x32_bf16(a1, b0, acc[1][0], 0,0,0);
        acc[1][1] = __builtin_amdgcn_mfma_f32_16x16x32_bf16(a1, b1, acc[1][1], 0,0,0);
    }
    #pragma unroll
    for (int rr=0; rr<2; rr++){
        #pragma unroll
        for (int cc=0; cc<2; cc++){
            int col = bn + wcol*32 + cc*16 + mr;
            if (MODE == 0){
                f16_t* op; size_t st;
                if (col < DIM){ op = out0 + col; st = DIM; }
                else          { op = out1 + (col - DIM); st = 2*DIM; }
                #pragma unroll
                for (int t=0; t<4; t++){
                    int row = bm + wrow*32 + rr*16 + quad*4 + t;
                    op[(size_t)row*st] = (f16_t)acc[rr][cc][t];
                }
            } else {
                float bv = bias[col];
                #pragma unroll
                for (int t=0; t<4; t++){
                    int row = bm + wrow*32 + rr*16 + quad*4 + t;
                    float z = acc[rr][cc][t] + bv;
                    ((bf16_t*)out0)[(size_t)row*MLPD + col] =
                        f2b(0.5f*z*(1.0f + erff(z*0.70710678118654752f)));
                }
            }
        }
    }
}

// ---------------- async GEMM + residual epilogue: xres += (A@B^T + bias)*ls ----
__global__ __launch_bounds__(256) void gemm_a_kernel(
        const ushort* __restrict__ A, const ushort* __restrict__ BT,
        const float* __restrict__ bias, const float* __restrict__ ls,
        float* __restrict__ xres, int K){
    __shared__ ushort As[2048];
    __shared__ ushort Bs[2048];
    int tid = threadIdx.x, lane = tid & 63, w = tid >> 6;
    int wrow = w >> 1, wcol = w & 1;
    int bm = blockIdx.x*64, bn = blockIdx.y*64;
    int quad = lane >> 4, mr = lane & 15;
    const ushort* ap = A  + (size_t)(bm + (tid>>2))*K + (tid&3)*8;
    const ushort* bp = BT + (size_t)(bn + (tid>>2))*K + (tid&3)*8;
    f32x4 acc[2][2] = {};
    for (int k0 = 0; k0 < K; k0 += 32){
        async16(&As[tid*8], ap + k0);
        async16(&Bs[tid*8], bp + k0);
        __syncthreads();
        short8 a0 = *(const short8*)&As[(wrow*32+mr)*32    + quad*8];
        short8 a1 = *(const short8*)&As[(wrow*32+16+mr)*32 + quad*8];
        short8 b0 = *(const short8*)&Bs[(wcol*32+mr)*32    + quad*8];
        short8 b1 = *(const short8*)&Bs[(wcol*32+16+mr)*32 + quad*8];
        acc[0][0] = __builtin_amdgcn_mfma_f32_16x16x32_bf16(a0, b0, acc[0][0], 0,0,0);
        acc[0][1] = __builtin_amdgcn_mfma_f32_16x16x32_bf16(a0, b1, acc[0][1], 0,0,0);
        acc[1][0] = __builtin_amdgcn_mfma_f32_16x16x32_bf16(a1, b0, acc[1][0], 0,0,0);
        acc[1][1] = __builtin_amdgcn_mfma_f32_16x16x32_bf16(a1, b1, acc[1][1], 0,0,0);
        __syncthreads();
    }
    #pragma unroll
    for (int rr=0; rr<2; rr++){
        #pragma unroll
        for (int cc=0; cc<2; cc++){
            int col = bn + wcol*32 + cc*16 + mr;
            float bv = bias[col], lv = ls[col];
            #pragma unroll
            for (int t=0; t<4; t++){
                int row = bm + wrow*32 + rr*16 + quad*4 + t;
                xres[(size_t)row*DIM + col] += (acc[rr][cc][t] + bv)*lv;
            }
        }
    }
}

// ---------------- fully-MFMA fused talking-heads LSA attention (unchanged) ----
#define SLAB    4488
#define IST     280
#define KV_OFF  53856
#define ROWP    200
#define Q_OFF   66656
#define PRE_OFF 69856
#define POST_OFF 70112
#define LTOT    71776

__global__ __launch_bounds__(512, 1) void attn_kernel(
        const f16_t* __restrict__ qb, const f16_t* __restrict__ kvb,
        const float* __restrict__ lsa, const float* __restrict__ pre,
        const float* __restrict__ post, bf16_t* __restrict__ ob){
    __shared__ ushort L[LTOT];
    int tid  = threadIdx.x;
    int lane = tid & 63, w = tid >> 6;
    int quad = lane >> 4, nr = lane & 15;
    int b  = blockIdx.x >> 4;
    int i0 = (blockIdx.x & 15) << 4;

    {
        uint* Z = (uint*)&L[KV_OFF];
        for (int k = tid; k < (LTOT - KV_OFF)/2; k += 512) Z[k] = 0;
    }
    __syncthreads();

    if (tid < 384){
        int e = tid*8, i = e/DIM, d = e%DIM, hh = d >> 4;
        float sc = lsa[hh];
        union { uint4 v; f16_t h[8]; } iv, ov;
        iv.v = *(const uint4*)(qb + (size_t)(b*SEQ + i0 + i)*DIM + d);
        #pragma unroll
        for (int u=0; u<8; u++) ov.h[u] = (f16_t)((float)iv.h[u]*sc);
        *(uint4*)&L[Q_OFF + i*ROWP + d] = ov.v;
    } else {
        for (int k = tid-384; k < 512; k += 128){
            int gg = (k & 255) >> 4, hh = k & 15;
            float v = 0.f;
            if (gg < 12 && hh < 12) v = (k < 256) ? pre[hh*12+gg] : post[hh*12+gg];
            L[(k < 256 ? PRE_OFF : (POST_OFF-256)) + k] = h2u((f16_t)v);
        }
    }
    auto stage_kv = [&](int c, int coloff){
        #pragma unroll
        for (int s = 0; s < 3; s++){
            int e = (tid + s*512)*8;
            int j = e/DIM, d = e%DIM;
            uint4 v = *(const uint4*)(kvb + (size_t)(b*SEQ + c*64 + j)*(2*DIM) + coloff + d);
            *(uint4*)&L[KV_OFF + j*ROWP + d] = v;
        }
    };
    stage_kv(0, 0);
    __syncthreads();

    int hbase = (w >> 2)*6;
    half4 qf[6];
    #pragma unroll
    for (int hh=0; hh<6; hh++)
        qf[hh] = *(const half4*)&L[Q_OFF + nr*ROWP + (hbase+hh)*16 + quad*4];
    half4 preTf  = *(const half4*)&L[PRE_OFF  + nr*16 + quad*4];
    half4 postTf = *(const half4*)&L[POST_OFF + nr*16 + quad*4];

    int jsl = w & 3;
    for (int c = 0; c < 4; c++){
        int j0g = c*64 + jsl*16;
        #pragma unroll
        for (int hh=0; hh<6; hh++){
            int h = hbase + hh;
            half4 bv = *(const half4*)&L[KV_OFF + (jsl*16 + nr)*ROWP + h*16 + quad*4];
            f32x4 a = __builtin_amdgcn_mfma_f32_16x16x16f16(qf[hh], bv, (f32x4){0,0,0,0}, 0,0,0);
            int jg = j0g + nr;
            #pragma unroll
            for (int t=0; t<4; t++){
                float v = a[t];
                if (i0 + quad*4 + t == jg) v = -1e-9f;
                L[h*SLAB + (quad*4+t)*IST + jg] = h2u((f16_t)v);
            }
        }
        __syncthreads();
        if (c < 3){ stage_kv(c+1, 0); __syncthreads(); }
    }

    for (int s = 0; s < 32; s++){
        int cb = s*8 + w;
        int i = cb >> 4, jb = cb & 15;
        int colbase = i*IST + jb*16 + nr;
        half4 bv;
        #pragma unroll
        for (int t=0; t<4; t++) bv[t] = u2h(L[(quad*4+t)*SLAB + colbase]);
        f32x4 cc = __builtin_amdgcn_mfma_f32_16x16x16f16(preTf, bv, (f32x4){0,0,0,0}, 0,0,0);
        if (quad < 3){
            #pragma unroll
            for (int t=0; t<4; t++) L[(quad*4+t)*SLAB + colbase] = h2u((f16_t)cc[t]);
        }
    }
    __syncthreads();

    for (int r = w; r < 192; r += 8){
        int g = r >> 4, i = r & 15;
        ushort* sp = &L[g*SLAB + i*IST];
        ushort4 uv = *(ushort4*)&sp[lane*4];
        float e0 = __expf((float)u2h(uv.x));
        float e1 = __expf((float)u2h(uv.y));
        float e2 = __expf((float)u2h(uv.z));
        float e3 = __expf((float)u2h(uv.w));
        float ssum = e0+e1+e2+e3;
        #pragma unroll
        for (int off=32; off; off>>=1) ssum += __shfl_xor(ssum, off, 64);
        float rin = 1.0f/ssum;
        uv.x = h2u((f16_t)(e0*rin)); uv.y = h2u((f16_t)(e1*rin));
        uv.z = h2u((f16_t)(e2*rin)); uv.w = h2u((f16_t)(e3*rin));
        *(ushort4*)&sp[lane*4] = uv;
    }
    __syncthreads();

    for (int s = 0; s < 32; s++){
        int cb = s*8 + w;
        int i = cb >> 4, jb = cb & 15;
        int colbase = i*IST + jb*16 + nr;
        half4 bv;
        #pragma unroll
        for (int t=0; t<4; t++) bv[t] = u2h(L[(quad*4+t)*SLAB + colbase]);
        f32x4 cc = __builtin_amdgcn_mfma_f32_16x16x16f16(postTf, bv, (f32x4){0,0,0,0}, 0,0,0);
        if (quad < 3){
            #pragma unroll
            for (int t=0; t<4; t++) L[(quad*4+t)*SLAB + colbase] = h2u((f16_t)cc[t]);
        }
    }
    __syncthreads();

    f32x4 oacc[2] = {{0,0,0,0},{0,0,0,0}};
    int g0 = w, g1 = (w < 4) ? 8 + w : -1;
    for (int c = 0; c < 4; c++){
        stage_kv(c, DIM);
        __syncthreads();
        #pragma unroll
        for (int sl = 0; sl < 2; sl++){
            int g = sl ? g1 : g0;
            if (g < 0) continue;
            #pragma unroll
            for (int ks = 0; ks < 4; ks++){
                int jl = ks*16 + quad*4;
                half4 av = *(const half4*)&L[g*SLAB + nr*IST + c*64 + jl];
                half4 bv;
                #pragma unroll
                for (int t=0; t<4; t++) bv[t] = u2h(L[KV_OFF + (jl+t)*ROWP + g*16 + nr]);
                oacc[sl] = __builtin_amdgcn_mfma_f32_16x16x16f16(av, bv, oacc[sl], 0,0,0);
            }
        }
        __syncthreads();
    }
    #pragma unroll
    for (int sl = 0; sl < 2; sl++){
        int g = sl ? g1 : g0;
        if (g < 0) continue;
        #pragma unroll
        for (int t=0; t<4; t++){
            int i = quad*4 + t;
            ob[(size_t)(b*SEQ + i0 + i)*DIM + g*16 + nr] = f2b(oacc[sl][t]);
        }
    }
}

extern "C" void kernel_launch(void* const* d_in, const int* in_sizes, int n_in,
                              void* d_out, int out_size, void* d_ws, size_t ws_size,
                              hipStream_t stream){
    const float* x    = (const float*)d_in[0];
    const float* ln1g = (const float*)d_in[1];
    const float* ln1b = (const float*)d_in[2];
    const float* Wq   = (const float*)d_in[3];
    const float* Wkv  = (const float*)d_in[4];
    const float* lsa  = (const float*)d_in[5];
    const float* pre  = (const float*)d_in[6];
    const float* post = (const float*)d_in[7];
    const float* Wo   = (const float*)d_in[8];
    const float* bo   = (const float*)d_in[9];
    const float* ls1  = (const float*)d_in[10];
    const float* ln2g = (const float*)d_in[11];
    const float* ln2b = (const float*)d_in[12];
    const float* W1   = (const float*)d_in[13];
    const float* b1   = (const float*)d_in[14];
    const float* W2   = (const float*)d_in[15];
    const float* b2   = (const float*)d_in[16];
    const float* ls2  = (const float*)d_in[17];
    float* xres = (float*)d_out;             // fp32 residual lives in d_out

    char* ws = (char*)d_ws;
    // union region: qb+kvb (QKV->attn) overlaps fb (W1->W2) — disjoint lifetimes
    f16_t*  qb  = (f16_t*)ws;
    f16_t*  kvb = (f16_t*)(ws + (size_t)ROWS*DIM*2);
    bf16_t* fb  = (bf16_t*)ws;
    char* p = ws + (size_t)ROWS*MLPD*2;
    bf16_t* ob  = (bf16_t*)p;  p += (size_t)ROWS*DIM*2;
    ushort* WqT  = (ushort*)p; p += (size_t)DEPTH*DIM*DIM*2;
    ushort* WkvT = (ushort*)p; p += (size_t)DEPTH*DIM*2*DIM*2;
    ushort* WoT  = (ushort*)p; p += (size_t)DEPTH*DIM*DIM*2;
    ushort* W1T  = (ushort*)p; p += (size_t)DEPTH*DIM*MLPD*2;
    ushort* W2T  = (ushort*)p; p += (size_t)DEPTH*MLPD*DIM*2;

    int ntot = ROWS*DIM;
    copy_kernel<<<ntot/256, 256, 0, stream>>>(x, xres, ntot);
    wt_kernel<<<dim3(3,3,6),  256, 0, stream>>>(Wq,  WqT,  DIM,  DIM);
    wt_kernel<<<dim3(3,6,6),  256, 0, stream>>>(Wkv, WkvT, DIM,  2*DIM);
    wt_kernel<<<dim3(3,3,6),  256, 0, stream>>>(Wo,  WoT,  DIM,  DIM);
    wt_kernel<<<dim3(3,12,6), 256, 0, stream>>>(W1,  W1T,  DIM,  MLPD);
    wt_kernel<<<dim3(12,3,6), 256, 0, stream>>>(W2,  W2T,  MLPD, DIM);
    for (int l = 0; l < DEPTH; l++){
        gemm_ln_kernel<0><<<dim3(128,9), 256, 0, stream>>>(xres,
                ln1g + l*DIM, ln1b + l*DIM,
                WqT + (size_t)l*DIM*DIM, WkvT + (size_t)l*DIM*2*DIM,
                nullptr, qb, kvb);
        attn_kernel<<<BATCH*(SEQ/16), 512, 0, stream>>>(qb, kvb, lsa + l*HEADS,
                pre + l*HEADS*HEADS, post + l*HEADS*HEADS, ob);
        gemm_a_kernel<<<dim3(128,3), 256, 0, stream>>>((const ushort*)ob,
                WoT + (size_t)l*DIM*DIM, bo + l*DIM, ls1 + l*DIM, xres, DIM);
        gemm_ln_kernel<1><<<dim3(128,12), 256, 0, stream>>>(xres,
                ln2g + l*DIM, ln2b + l*DIM,
                W1T + (size_t)l*DIM*MLPD, nullptr, b1 + l*MLPD, (f16_t*)fb, nullptr);
        gemm_a_kernel<<<dim3(128,3), 256, 0, stream>>>((const ushort*)fb,
                W2T + (size_t)l*MLPD*DIM, b2 + l*DIM, ls2 + l*DIM, xres, MLPD);
    }
}

// Round 5
// 857.009 us; speedup vs baseline: 1.0063x; 1.0063x over previous
//
#include <hip/hip_runtime.h>
#include <hip/hip_bf16.h>

#define DEPTH   6
#define DIM     192
#define HEADS   12
#define DH      16
#define MLPD    768
#define SEQ     256
#define BATCH   32
#define ROWS    (BATCH*SEQ)   // 8192

typedef __attribute__((ext_vector_type(8))) short short8;
typedef __attribute__((ext_vector_type(4))) float f32x4;
typedef __attribute__((ext_vector_type(4))) _Float16 half4;
typedef __hip_bfloat16 bf16_t;
typedef _Float16 f16_t;

__device__ __forceinline__ bf16_t f2b(float v){ return __float2bfloat16(v); }
__device__ __forceinline__ ushort f2u(float v){
    union{ bf16_t b; ushort u; } w; w.b = __float2bfloat16(v); return w.u;
}
__device__ __forceinline__ f16_t u2h(ushort u){ union{ ushort u; f16_t h; } w; w.u = u; return w.h; }
__device__ __forceinline__ ushort h2u(f16_t h){ union{ ushort u; f16_t h; } w; w.h = h; return w.u; }

// async global->LDS, 16B per lane. LDS dest = wave-uniform base + lane*16B.
__device__ __forceinline__ void async16(ushort* lds, const ushort* gp){
    __builtin_amdgcn_global_load_lds(
        (const __attribute__((address_space(1))) uint*)gp,
        (__attribute__((address_space(3))) uint*)lds, 16, 0, 0);
}

// ---------------- residual init ----------------
__global__ void copy_kernel(const float* __restrict__ x, float* __restrict__ xr, int n){
    int i = blockIdx.x*256 + threadIdx.x;
    if (i < n) xr[i] = x[i];
}

// ---------------- weight transpose-convert: W[l][K][N] fp32 -> WT[l][N][K] bf16 ----
__global__ __launch_bounds__(256) void wt_kernel(const float* __restrict__ W,
        ushort* __restrict__ WT, int K, int N){
    __shared__ ushort T[64*72];
    int l = blockIdx.z;
    const float* src = W + ((size_t)l*K + blockIdx.x*64)*N + blockIdx.y*64;
    ushort* dst = WT + ((size_t)l*N + blockIdx.y*64)*K + blockIdx.x*64;
    int tid = threadIdx.x;
    int r = tid >> 2, c4 = (tid & 3)*16;
    #pragma unroll
    for (int u=0; u<4; u++){
        float4 v = *(const float4*)(src + (size_t)r*N + c4 + u*4);
        T[(c4+u*4+0)*72 + r] = f2u(v.x);
        T[(c4+u*4+1)*72 + r] = f2u(v.y);
        T[(c4+u*4+2)*72 + r] = f2u(v.z);
        T[(c4+u*4+3)*72 + r] = f2u(v.w);
    }
    __syncthreads();
    int n = tid >> 2, k8 = (tid & 3)*16;
    #pragma unroll
    for (int u=0; u<2; u++)
        *(uint4*)(dst + (size_t)n*K + k8 + u*8) = *(uint4*)&T[n*72 + k8 + u*8];
}

// ---------------- fused LN + GEMM, column-looping (K = DIM = 192) ----------------
// MODE 0: QKV -> out0 (f16 stride 192) for cols<192, else out1 (f16 stride 384)
// MODE 1: W1  -> +bias, exact GELU, bf16 to out0 (stride MLPD)
template<int MODE, int NT>
__global__ __launch_bounds__(256) void gemm_ln_kernel(
        const float* __restrict__ xres, const float* __restrict__ ln_g,
        const float* __restrict__ ln_b, const ushort* __restrict__ BT0,
        const ushort* __restrict__ BT1, const float* __restrict__ bias,
        f16_t* __restrict__ out0, f16_t* __restrict__ out1){
    __shared__ ushort As[64*200];      // LN'd A rows, stride 200 (2-way banks)
    __shared__ ushort Bs[2][6*2048];   // double-buffered N-tile (full K, packed 32k)
    int tid = threadIdx.x, lane = tid & 63, w = tid >> 6;
    int bm = blockIdx.x*64;
    int tile0 = blockIdx.y*NT;
    auto issueB = [&](int t, int buf){
        int bn = (tile0 + t)*64;
        const ushort* bt; int bnl;
        if (MODE == 0 && bn >= DIM){ bt = BT1; bnl = bn - DIM; }
        else { bt = BT0; bnl = bn; }
        const ushort* bp = bt + (size_t)(bnl + (tid>>2))*DIM + (tid&3)*8;
        #pragma unroll
        for (int c=0; c<6; c++)
            async16(&Bs[buf][c*2048 + tid*8], bp + c*32);
    };
    issueB(0, 0);
    // LN prologue: each block LNs its 64 rows ONCE
    float g0 = ln_g[lane], g1 = ln_g[lane+64], g2 = ln_g[lane+128];
    float e0 = ln_b[lane], e1 = ln_b[lane+64], e2 = ln_b[lane+128];
    for (int it = 0; it < 16; it++){
        int r = (w<<4) + it;
        const float* xr = xres + (size_t)(bm + r)*DIM;
        float v0 = xr[lane], v1 = xr[lane+64], v2 = xr[lane+128];
        float s = v0+v1+v2;
        #pragma unroll
        for (int off=32; off; off>>=1) s += __shfl_xor(s, off, 64);
        float m = s*(1.0f/192.0f);
        float d0=v0-m, d1=v1-m, d2=v2-m;
        float q = d0*d0+d1*d1+d2*d2;
        #pragma unroll
        for (int off=32; off; off>>=1) q += __shfl_xor(q, off, 64);
        float inv = rsqrtf(q*(1.0f/192.0f) + 1e-5f);
        ushort* dst = &As[r*200];
        dst[lane]     = f2u(d0*inv*g0 + e0);
        dst[lane+64]  = f2u(d1*inv*g1 + e1);
        dst[lane+128] = f2u(d2*inv*g2 + e2);
    }
    __syncthreads();   // drains tile-0 asyncs + As visible
    int wrow = w >> 1, wcol = w & 1;
    int quad = lane >> 4, mr = lane & 15;
    for (int t = 0; t < NT; t++){
        if (t+1 < NT) issueB(t+1, (t+1)&1);
        const ushort* B = Bs[t&1];
        f32x4 acc[2][2] = {};
        #pragma unroll
        for (int c = 0; c < 6; c++){
            short8 a0 = *(const short8*)&As[(wrow*32+mr)*200    + c*32 + quad*8];
            short8 a1 = *(const short8*)&As[(wrow*32+16+mr)*200 + c*32 + quad*8];
            short8 b0 = *(const short8*)&B[c*2048 + (wcol*32+mr)*32    + quad*8];
            short8 b1 = *(const short8*)&B[c*2048 + (wcol*32+16+mr)*32 + quad*8];
            acc[0][0] = __builtin_amdgcn_mfma_f32_16x16x32_bf16(a0, b0, acc[0][0], 0,0,0);
            acc[0][1] = __builtin_amdgcn_mfma_f32_16x16x32_bf16(a0, b1, acc[0][1], 0,0,0);
            acc[1][0] = __builtin_amdgcn_mfma_f32_16x16x32_bf16(a1, b0, acc[1][0], 0,0,0);
            acc[1][1] = __builtin_amdgcn_mfma_f32_16x16x32_bf16(a1, b1, acc[1][1], 0,0,0);
        }
        int bn = (tile0 + t)*64;
        #pragma unroll
        for (int rr=0; rr<2; rr++){
            #pragma unroll
            for (int cc=0; cc<2; cc++){
                int col = bn + wcol*32 + cc*16 + mr;
                if (MODE == 0){
                    f16_t* op; size_t st;
                    if (col < DIM){ op = out0 + col; st = DIM; }
                    else          { op = out1 + (col - DIM); st = 2*DIM; }
                    #pragma unroll
                    for (int tt=0; tt<4; tt++){
                        int row = bm + wrow*32 + rr*16 + quad*4 + tt;
                        op[(size_t)row*st] = (f16_t)acc[rr][cc][tt];
                    }
                } else {
                    float bv = bias[col];
                    #pragma unroll
                    for (int tt=0; tt<4; tt++){
                        int row = bm + wrow*32 + rr*16 + quad*4 + tt;
                        float z = acc[rr][cc][tt] + bv;
                        ((bf16_t*)out0)[(size_t)row*MLPD + col] =
                            f2b(0.5f*z*(1.0f + erff(z*0.70710678118654752f)));
                    }
                }
            }
        }
        __syncthreads();
    }
}

// ---------------- GEMM + residual epilogue: xres += (A@B^T + bias)*ls ----------
// ROUNDS rounds of 6 k-tiles (192 k per barrier-pair, 24 MFMAs/round)
template<int ROUNDS>
__global__ __launch_bounds__(256) void gemm_a_kernel(
        const ushort* __restrict__ A, const ushort* __restrict__ BT,
        const float* __restrict__ bias, const float* __restrict__ ls,
        float* __restrict__ xres){
    const int K = ROUNDS*192;
    __shared__ ushort As[6*2048];
    __shared__ ushort Bs[6*2048];
    int tid = threadIdx.x, lane = tid & 63, w = tid >> 6;
    int wrow = w >> 1, wcol = w & 1;
    int bm = blockIdx.x*64, bn = blockIdx.y*64;
    int quad = lane >> 4, mr = lane & 15;
    const ushort* ap = A  + (size_t)(bm + (tid>>2))*K + (tid&3)*8;
    const ushort* bp = BT + (size_t)(bn + (tid>>2))*K + (tid&3)*8;
    f32x4 acc[2][2] = {};
    for (int r = 0; r < ROUNDS; r++){
        #pragma unroll
        for (int c=0; c<6; c++){
            async16(&As[c*2048 + tid*8], ap + r*192 + c*32);
            async16(&Bs[c*2048 + tid*8], bp + r*192 + c*32);
        }
        __syncthreads();
        #pragma unroll
        for (int c=0; c<6; c++){
            short8 a0 = *(const short8*)&As[c*2048 + (wrow*32+mr)*32    + quad*8];
            short8 a1 = *(const short8*)&As[c*2048 + (wrow*32+16+mr)*32 + quad*8];
            short8 b0 = *(const short8*)&Bs[c*2048 + (wcol*32+mr)*32    + quad*8];
            short8 b1 = *(const short8*)&Bs[c*2048 + (wcol*32+16+mr)*32 + quad*8];
            acc[0][0] = __builtin_amdgcn_mfma_f32_16x16x32_bf16(a0, b0, acc[0][0], 0,0,0);
            acc[0][1] = __builtin_amdgcn_mfma_f32_16x16x32_bf16(a0, b1, acc[0][1], 0,0,0);
            acc[1][0] = __builtin_amdgcn_mfma_f32_16x16x32_bf16(a1, b0, acc[1][0], 0,0,0);
            acc[1][1] = __builtin_amdgcn_mfma_f32_16x16x32_bf16(a1, b1, acc[1][1], 0,0,0);
        }
        if (r+1 < ROUNDS) __syncthreads();
    }
    #pragma unroll
    for (int rr=0; rr<2; rr++){
        #pragma unroll
        for (int cc=0; cc<2; cc++){
            int col = bn + wcol*32 + cc*16 + mr;
            float bv = bias[col], lv = ls[col];
            #pragma unroll
            for (int tt=0; tt<4; tt++){
                int row = bm + wrow*32 + rr*16 + quad*4 + tt;
                xres[(size_t)row*DIM + col] += (acc[rr][cc][tt] + bv)*lv;
            }
        }
    }
}

// ---------------- fully-MFMA fused talking-heads LSA attention ----------------
// block = (batch, 8-row i-tile), 256 threads / 4 waves, 1024 blocks, 2 blocks/CU.
// LDS (ushort units): S[h][i][j] at h*SLAB + i*IST + j (h<12, i<8, j<256).
// mix MFMAs read h=0..15: rows 12..15 land past S in staged/zeroed finite regions.
#define SLAB    2152       // 8*268 + 8
#define IST     268
#define KV_OFF  25824      // 12*SLAB
#define ROWP    200
#define Q_OFF   32224      // KV_OFF + 32*ROWP
#define PRE_OFF 35424      // Q_OFF + 16*ROWP
#define POST_OFF 35680
#define LTOT    35936

__global__ __launch_bounds__(256, 2) void attn_kernel(
        const f16_t* __restrict__ qb, const f16_t* __restrict__ kvb,
        const float* __restrict__ lsa, const float* __restrict__ pre,
        const float* __restrict__ post, bf16_t* __restrict__ ob){
    __shared__ ushort L[LTOT];
    int tid  = threadIdx.x;
    int lane = tid & 63, w = tid >> 6;
    int quad = lane >> 4, nr = lane & 15;
    int b  = blockIdx.x >> 5;
    int i0 = (blockIdx.x & 31) << 3;

    // zero-fill all LDS (OOB-read safety: every readable address stays finite)
    {
        uint* Z = (uint*)L;
        for (int k = tid; k < LTOT/2; k += 256) Z[k] = 0;
    }
    __syncthreads();

    // stage Q rows (lsa folded) with tid<192; preT/postT zero-padded with tid>=192
    if (tid < 192){
        int e = tid*8, i = e/DIM, d = e%DIM, hh = d >> 4;
        float sc = lsa[hh];
        union { uint4 v; f16_t h[8]; } iv, ov;
        iv.v = *(const uint4*)(qb + (size_t)(b*SEQ + i0 + i)*DIM + d);
        #pragma unroll
        for (int u=0; u<8; u++) ov.h[u] = (f16_t)((float)iv.h[u]*sc);
        *(uint4*)&L[Q_OFF + i*ROWP + d] = ov.v;
    } else {
        for (int k = tid-192; k < 512; k += 64){
            int kk = k & 255, gg = kk >> 4, hh = kk & 15;
            if (gg < 12 && hh < 12){
                float v = (k < 256) ? pre[hh*12+gg] : post[hh*12+gg];
                L[(k < 256 ? PRE_OFF : POST_OFF) + kk] = h2u((f16_t)v);
            }
        }
    }
    // stage K/V 32-row chunk (all 256 threads)
    auto stage_kv = [&](int c, int coloff){
        #pragma unroll
        for (int s = 0; s < 3; s++){
            int e = (tid + s*256)*8;
            int j = e/DIM, d = e%DIM;
            uint4 v = *(const uint4*)(kvb + (size_t)(b*SEQ + c*32 + j)*(2*DIM) + coloff + d);
            *(uint4*)&L[KV_OFF + j*ROWP + d] = v;
        }
    };
    stage_kv(0, 0);
    __syncthreads();

    // persistent frags: wave w owns heads {w, w+4, w+8}
    half4 qf[3];
    #pragma unroll
    for (int hh=0; hh<3; hh++)
        qf[hh] = *(const half4*)&L[Q_OFF + nr*ROWP + (w + hh*4)*16 + quad*4];
    half4 preTf  = *(const half4*)&L[PRE_OFF  + nr*16 + quad*4];
    half4 postTf = *(const half4*)&L[POST_OFF + nr*16 + quad*4];

    // ---- P1: QK^T, diag fix, logits -> S (f16). 8 chunks of 32 j ----
    for (int c = 0; c < 8; c++){
        #pragma unroll
        for (int hh=0; hh<3; hh++){
            int h = w + hh*4;
            #pragma unroll
            for (int jb2=0; jb2<2; jb2++){
                half4 bv = *(const half4*)&L[KV_OFF + (jb2*16 + nr)*ROWP + h*16 + quad*4];
                f32x4 a = __builtin_amdgcn_mfma_f32_16x16x16f16(qf[hh], bv, (f32x4){0,0,0,0}, 0,0,0);
                int jg = c*32 + jb2*16 + nr;
                if (quad < 2){
                    #pragma unroll
                    for (int t=0; t<4; t++){
                        int i = quad*4 + t;
                        float v = a[t];
                        if (i0 + i == jg) v = -1e-9f;
                        L[h*SLAB + i*IST + jg] = h2u((f16_t)v);
                    }
                }
            }
        }
        __syncthreads();
        if (c < 7){ stage_kv(c+1, 0); __syncthreads(); }
    }

    // ---- P2: mix_pre via MFMA, in-place per (i, j-16) column-block ----
    for (int s = 0; s < 32; s++){
        int cb = s*4 + w;
        int i = cb >> 4, jb = cb & 15;
        int colbase = i*IST + jb*16 + nr;
        half4 bv;
        #pragma unroll
        for (int t=0; t<4; t++) bv[t] = u2h(L[(quad*4+t)*SLAB + colbase]);
        f32x4 cc = __builtin_amdgcn_mfma_f32_16x16x16f16(preTf, bv, (f32x4){0,0,0,0}, 0,0,0);
        if (quad < 3){
            #pragma unroll
            for (int t=0; t<4; t++) L[(quad*4+t)*SLAB + colbase] = h2u((f16_t)cc[t]);
        }
    }
    __syncthreads();

    // ---- softmax over j (mixed logits are O(1): no max-sub needed) ----
    for (int r = w; r < 96; r += 4){
        int g = r >> 3, i = r & 7;
        ushort* sp = &L[g*SLAB + i*IST];
        ushort4 uv = *(ushort4*)&sp[lane*4];
        float e0 = __expf((float)u2h(uv.x));
        float e1 = __expf((float)u2h(uv.y));
        float e2 = __expf((float)u2h(uv.z));
        float e3 = __expf((float)u2h(uv.w));
        float ssum = e0+e1+e2+e3;
        #pragma unroll
        for (int off=32; off; off>>=1) ssum += __shfl_xor(ssum, off, 64);
        float rin = 1.0f/ssum;
        uv.x = h2u((f16_t)(e0*rin)); uv.y = h2u((f16_t)(e1*rin));
        uv.z = h2u((f16_t)(e2*rin)); uv.w = h2u((f16_t)(e3*rin));
        *(ushort4*)&sp[lane*4] = uv;
    }
    __syncthreads();

    // ---- P3: mix_post via MFMA, in-place ----
    for (int s = 0; s < 32; s++){
        int cb = s*4 + w;
        int i = cb >> 4, jb = cb & 15;
        int colbase = i*IST + jb*16 + nr;
        half4 bv;
        #pragma unroll
        for (int t=0; t<4; t++) bv[t] = u2h(L[(quad*4+t)*SLAB + colbase]);
        f32x4 cc = __builtin_amdgcn_mfma_f32_16x16x16f16(postTf, bv, (f32x4){0,0,0,0}, 0,0,0);
        if (quad < 3){
            #pragma unroll
            for (int t=0; t<4; t++) L[(quad*4+t)*SLAB + colbase] = h2u((f16_t)cc[t]);
        }
    }
    __syncthreads();

    // ---- P4: O = P @ V. wave w owns heads {w, w+4, w+8} ----
    f32x4 oacc[3] = {{0,0,0,0},{0,0,0,0},{0,0,0,0}};
    for (int c = 0; c < 8; c++){
        stage_kv(c, DIM);
        __syncthreads();
        #pragma unroll
        for (int gg = 0; gg < 3; gg++){
            int g = w + gg*4;
            #pragma unroll
            for (int ks = 0; ks < 2; ks++){
                int jl = ks*16 + quad*4;
                half4 av = *(const half4*)&L[g*SLAB + nr*IST + c*32 + jl];
                half4 bv;
                #pragma unroll
                for (int t=0; t<4; t++) bv[t] = u2h(L[KV_OFF + (jl+t)*ROWP + g*16 + nr]);
                oacc[gg] = __builtin_amdgcn_mfma_f32_16x16x16f16(av, bv, oacc[gg], 0,0,0);
            }
        }
        __syncthreads();
    }
    if (quad < 2){
        #pragma unroll
        for (int gg = 0; gg < 3; gg++){
            int g = w + gg*4;
            #pragma unroll
            for (int t=0; t<4; t++){
                int i = quad*4 + t;
                ob[(size_t)(b*SEQ + i0 + i)*DIM + g*16 + nr] = f2b(oacc[gg][t]);
            }
        }
    }
}

extern "C" void kernel_launch(void* const* d_in, const int* in_sizes, int n_in,
                              void* d_out, int out_size, void* d_ws, size_t ws_size,
                              hipStream_t stream){
    const float* x    = (const float*)d_in[0];
    const float* ln1g = (const float*)d_in[1];
    const float* ln1b = (const float*)d_in[2];
    const float* Wq   = (const float*)d_in[3];
    const float* Wkv  = (const float*)d_in[4];
    const float* lsa  = (const float*)d_in[5];
    const float* pre  = (const float*)d_in[6];
    const float* post = (const float*)d_in[7];
    const float* Wo   = (const float*)d_in[8];
    const float* bo   = (const float*)d_in[9];
    const float* ls1  = (const float*)d_in[10];
    const float* ln2g = (const float*)d_in[11];
    const float* ln2b = (const float*)d_in[12];
    const float* W1   = (const float*)d_in[13];
    const float* b1   = (const float*)d_in[14];
    const float* W2   = (const float*)d_in[15];
    const float* b2   = (const float*)d_in[16];
    const float* ls2  = (const float*)d_in[17];
    float* xres = (float*)d_out;             // fp32 residual lives in d_out

    char* ws = (char*)d_ws;
    // union region: qb+kvb (QKV->attn) overlaps fb (W1->W2) — disjoint lifetimes
    f16_t*  qb  = (f16_t*)ws;
    f16_t*  kvb = (f16_t*)(ws + (size_t)ROWS*DIM*2);
    bf16_t* fb  = (bf16_t*)ws;
    char* p = ws + (size_t)ROWS*MLPD*2;
    bf16_t* ob  = (bf16_t*)p;  p += (size_t)ROWS*DIM*2;
    ushort* WqT  = (ushort*)p; p += (size_t)DEPTH*DIM*DIM*2;
    ushort* WkvT = (ushort*)p; p += (size_t)DEPTH*DIM*2*DIM*2;
    ushort* WoT  = (ushort*)p; p += (size_t)DEPTH*DIM*DIM*2;
    ushort* W1T  = (ushort*)p; p += (size_t)DEPTH*DIM*MLPD*2;
    ushort* W2T  = (ushort*)p; p += (size_t)DEPTH*MLPD*DIM*2;

    int ntot = ROWS*DIM;
    copy_kernel<<<ntot/256, 256, 0, stream>>>(x, xres, ntot);
    wt_kernel<<<dim3(3,3,6),  256, 0, stream>>>(Wq,  WqT,  DIM,  DIM);
    wt_kernel<<<dim3(3,6,6),  256, 0, stream>>>(Wkv, WkvT, DIM,  2*DIM);
    wt_kernel<<<dim3(3,3,6),  256, 0, stream>>>(Wo,  WoT,  DIM,  DIM);
    wt_kernel<<<dim3(3,12,6), 256, 0, stream>>>(W1,  W1T,  DIM,  MLPD);
    wt_kernel<<<dim3(12,3,6), 256, 0, stream>>>(W2,  W2T,  MLPD, DIM);
    for (int l = 0; l < DEPTH; l++){
        gemm_ln_kernel<0,3><<<dim3(128,3), 256, 0, stream>>>(xres,
                ln1g + l*DIM, ln1b + l*DIM,
                WqT + (size_t)l*DIM*DIM, WkvT + (size_t)l*DIM*2*DIM,
                nullptr, qb, kvb);
        attn_kernel<<<BATCH*(SEQ/8), 256, 0, stream>>>(qb, kvb, lsa + l*HEADS,
                pre + l*HEADS*HEADS, post + l*HEADS*HEADS, ob);
        gemm_a_kernel<1><<<dim3(128,3), 256, 0, stream>>>((const ushort*)ob,
                WoT + (size_t)l*DIM*DIM, bo + l*DIM, ls1 + l*DIM, xres);
        gemm_ln_kernel<1,4><<<dim3(128,3), 256, 0, stream>>>(xres,
                ln2g + l*DIM, ln2b + l*DIM,
                W1T + (size_t)l*DIM*MLPD, nullptr, b1 + l*MLPD, (f16_t*)fb, nullptr);
        gemm_a_kernel<4><<<dim3(128,3), 256, 0, stream>>>((const ushort*)fb,
                W2T + (size_t)l*MLPD*DIM, b2 + l*DIM, ls2 + l*DIM, xres);
    }
}

// Round 6
// 753.758 us; speedup vs baseline: 1.1442x; 1.1370x over previous
//
#include <hip/hip_runtime.h>
#include <hip/hip_bf16.h>

#define DEPTH   6
#define DIM     192
#define HEADS   12
#define DH      16
#define MLPD    768
#define SEQ     256
#define BATCH   32
#define ROWS    (BATCH*SEQ)   // 8192

typedef __attribute__((ext_vector_type(8))) short short8;
typedef __attribute__((ext_vector_type(4))) float f32x4;
typedef __attribute__((ext_vector_type(4))) _Float16 half4;
typedef __hip_bfloat16 bf16_t;
typedef _Float16 f16_t;

__device__ __forceinline__ bf16_t f2b(float v){ return __float2bfloat16(v); }
__device__ __forceinline__ ushort f2u(float v){
    union{ bf16_t b; ushort u; } w; w.b = __float2bfloat16(v); return w.u;
}
__device__ __forceinline__ f16_t u2h(ushort u){ union{ ushort u; f16_t h; } w; w.u = u; return w.h; }
__device__ __forceinline__ ushort h2u(f16_t h){ union{ ushort u; f16_t h; } w; w.h = h; return w.u; }

// async global->LDS, 16B per lane. LDS dest = wave-uniform base + lane*16B.
__device__ __forceinline__ void async16(ushort* lds, const ushort* gp){
    __builtin_amdgcn_global_load_lds(
        (const __attribute__((address_space(1))) uint*)gp,
        (__attribute__((address_space(3))) uint*)lds, 16, 0, 0);
}

// ---------------- residual init ----------------
__global__ void copy_kernel(const float* __restrict__ x, float* __restrict__ xr, int n){
    int i = blockIdx.x*256 + threadIdx.x;
    if (i < n) xr[i] = x[i];
}

// ---------------- weight transpose-convert: W[l][K][N] fp32 -> WT[l][N][K] bf16 ----
__global__ __launch_bounds__(256) void wt_kernel(const float* __restrict__ W,
        ushort* __restrict__ WT, int K, int N){
    __shared__ ushort T[64*72];
    int l = blockIdx.z;
    const float* src = W + ((size_t)l*K + blockIdx.x*64)*N + blockIdx.y*64;
    ushort* dst = WT + ((size_t)l*N + blockIdx.y*64)*K + blockIdx.x*64;
    int tid = threadIdx.x;
    int r = tid >> 2, c4 = (tid & 3)*16;
    #pragma unroll
    for (int u=0; u<4; u++){
        float4 v = *(const float4*)(src + (size_t)r*N + c4 + u*4);
        T[(c4+u*4+0)*72 + r] = f2u(v.x);
        T[(c4+u*4+1)*72 + r] = f2u(v.y);
        T[(c4+u*4+2)*72 + r] = f2u(v.z);
        T[(c4+u*4+3)*72 + r] = f2u(v.w);
    }
    __syncthreads();
    int n = tid >> 2, k8 = (tid & 3)*16;
    #pragma unroll
    for (int u=0; u<2; u++)
        *(uint4*)(dst + (size_t)n*K + k8 + u*8) = *(uint4*)&T[n*72 + k8 + u*8];
}

// ---------------- fused LN + GEMM, column-looping (K = DIM = 192) ----------------
// MODE 0: QKV -> out0 (f16 stride 192) for cols<192, else out1 (f16 stride 384)
// MODE 1: W1  -> +bias, exact GELU, bf16 to out0 (stride MLPD)
template<int MODE, int NT>
__global__ __launch_bounds__(256) void gemm_ln_kernel(
        const float* __restrict__ xres, const float* __restrict__ ln_g,
        const float* __restrict__ ln_b, const ushort* __restrict__ BT0,
        const ushort* __restrict__ BT1, const float* __restrict__ bias,
        f16_t* __restrict__ out0, f16_t* __restrict__ out1){
    __shared__ ushort As[64*200];      // LN'd A rows, stride 200 (2-way banks)
    __shared__ ushort Bs[2][6*2048];   // double-buffered N-tile (full K, packed 32k)
    int tid = threadIdx.x, lane = tid & 63, w = tid >> 6;
    int bm = blockIdx.x*64;
    int tile0 = blockIdx.y*NT;
    auto issueB = [&](int t, int buf){
        int bn = (tile0 + t)*64;
        const ushort* bt; int bnl;
        if (MODE == 0 && bn >= DIM){ bt = BT1; bnl = bn - DIM; }
        else { bt = BT0; bnl = bn; }
        const ushort* bp = bt + (size_t)(bnl + (tid>>2))*DIM + (tid&3)*8;
        #pragma unroll
        for (int c=0; c<6; c++)
            async16(&Bs[buf][c*2048 + tid*8], bp + c*32);
    };
    issueB(0, 0);
    // LN prologue: each block LNs its 64 rows ONCE
    float g0 = ln_g[lane], g1 = ln_g[lane+64], g2 = ln_g[lane+128];
    float e0 = ln_b[lane], e1 = ln_b[lane+64], e2 = ln_b[lane+128];
    for (int it = 0; it < 16; it++){
        int r = (w<<4) + it;
        const float* xr = xres + (size_t)(bm + r)*DIM;
        float v0 = xr[lane], v1 = xr[lane+64], v2 = xr[lane+128];
        float s = v0+v1+v2;
        #pragma unroll
        for (int off=32; off; off>>=1) s += __shfl_xor(s, off, 64);
        float m = s*(1.0f/192.0f);
        float d0=v0-m, d1=v1-m, d2=v2-m;
        float q = d0*d0+d1*d1+d2*d2;
        #pragma unroll
        for (int off=32; off; off>>=1) q += __shfl_xor(q, off, 64);
        float inv = rsqrtf(q*(1.0f/192.0f) + 1e-5f);
        ushort* dst = &As[r*200];
        dst[lane]     = f2u(d0*inv*g0 + e0);
        dst[lane+64]  = f2u(d1*inv*g1 + e1);
        dst[lane+128] = f2u(d2*inv*g2 + e2);
    }
    __syncthreads();   // drains tile-0 asyncs + As visible
    int wrow = w >> 1, wcol = w & 1;
    int quad = lane >> 4, mr = lane & 15;
    for (int t = 0; t < NT; t++){
        if (t+1 < NT) issueB(t+1, (t+1)&1);
        const ushort* B = Bs[t&1];
        f32x4 acc[2][2] = {};
        #pragma unroll
        for (int c = 0; c < 6; c++){
            short8 a0 = *(const short8*)&As[(wrow*32+mr)*200    + c*32 + quad*8];
            short8 a1 = *(const short8*)&As[(wrow*32+16+mr)*200 + c*32 + quad*8];
            short8 b0 = *(const short8*)&B[c*2048 + (wcol*32+mr)*32    + quad*8];
            short8 b1 = *(const short8*)&B[c*2048 + (wcol*32+16+mr)*32 + quad*8];
            acc[0][0] = __builtin_amdgcn_mfma_f32_16x16x32_bf16(a0, b0, acc[0][0], 0,0,0);
            acc[0][1] = __builtin_amdgcn_mfma_f32_16x16x32_bf16(a0, b1, acc[0][1], 0,0,0);
            acc[1][0] = __builtin_amdgcn_mfma_f32_16x16x32_bf16(a1, b0, acc[1][0], 0,0,0);
            acc[1][1] = __builtin_amdgcn_mfma_f32_16x16x32_bf16(a1, b1, acc[1][1], 0,0,0);
        }
        int bn = (tile0 + t)*64;
        #pragma unroll
        for (int rr=0; rr<2; rr++){
            #pragma unroll
            for (int cc=0; cc<2; cc++){
                int col = bn + wcol*32 + cc*16 + mr;
                if (MODE == 0){
                    f16_t* op; size_t st;
                    if (col < DIM){ op = out0 + col; st = DIM; }
                    else          { op = out1 + (col - DIM); st = 2*DIM; }
                    #pragma unroll
                    for (int tt=0; tt<4; tt++){
                        int row = bm + wrow*32 + rr*16 + quad*4 + tt;
                        op[(size_t)row*st] = (f16_t)acc[rr][cc][tt];
                    }
                } else {
                    float bv = bias[col];
                    #pragma unroll
                    for (int tt=0; tt<4; tt++){
                        int row = bm + wrow*32 + rr*16 + quad*4 + tt;
                        float z = acc[rr][cc][tt] + bv;
                        ((bf16_t*)out0)[(size_t)row*MLPD + col] =
                            f2b(0.5f*z*(1.0f + erff(z*0.70710678118654752f)));
                    }
                }
            }
        }
        __syncthreads();
    }
}

// ---------------- GEMM + residual epilogue: xres += (A@B^T + bias)*ls ----------
// ROUNDS rounds of 6 k-tiles (192 k per barrier-pair, 24 MFMAs/round)
template<int ROUNDS>
__global__ __launch_bounds__(256) void gemm_a_kernel(
        const ushort* __restrict__ A, const ushort* __restrict__ BT,
        const float* __restrict__ bias, const float* __restrict__ ls,
        float* __restrict__ xres){
    const int K = ROUNDS*192;
    __shared__ ushort As[6*2048];
    __shared__ ushort Bs[6*2048];
    int tid = threadIdx.x, lane = tid & 63, w = tid >> 6;
    int wrow = w >> 1, wcol = w & 1;
    int bm = blockIdx.x*64, bn = blockIdx.y*64;
    int quad = lane >> 4, mr = lane & 15;
    const ushort* ap = A  + (size_t)(bm + (tid>>2))*K + (tid&3)*8;
    const ushort* bp = BT + (size_t)(bn + (tid>>2))*K + (tid&3)*8;
    f32x4 acc[2][2] = {};
    for (int r = 0; r < ROUNDS; r++){
        #pragma unroll
        for (int c=0; c<6; c++){
            async16(&As[c*2048 + tid*8], ap + r*192 + c*32);
            async16(&Bs[c*2048 + tid*8], bp + r*192 + c*32);
        }
        __syncthreads();
        #pragma unroll
        for (int c=0; c<6; c++){
            short8 a0 = *(const short8*)&As[c*2048 + (wrow*32+mr)*32    + quad*8];
            short8 a1 = *(const short8*)&As[c*2048 + (wrow*32+16+mr)*32 + quad*8];
            short8 b0 = *(const short8*)&Bs[c*2048 + (wcol*32+mr)*32    + quad*8];
            short8 b1 = *(const short8*)&Bs[c*2048 + (wcol*32+16+mr)*32 + quad*8];
            acc[0][0] = __builtin_amdgcn_mfma_f32_16x16x32_bf16(a0, b0, acc[0][0], 0,0,0);
            acc[0][1] = __builtin_amdgcn_mfma_f32_16x16x32_bf16(a0, b1, acc[0][1], 0,0,0);
            acc[1][0] = __builtin_amdgcn_mfma_f32_16x16x32_bf16(a1, b0, acc[1][0], 0,0,0);
            acc[1][1] = __builtin_amdgcn_mfma_f32_16x16x32_bf16(a1, b1, acc[1][1], 0,0,0);
        }
        if (r+1 < ROUNDS) __syncthreads();
    }
    #pragma unroll
    for (int rr=0; rr<2; rr++){
        #pragma unroll
        for (int cc=0; cc<2; cc++){
            int col = bn + wcol*32 + cc*16 + mr;
            float bv = bias[col], lv = ls[col];
            #pragma unroll
            for (int tt=0; tt<4; tt++){
                int row = bm + wrow*32 + rr*16 + quad*4 + tt;
                xres[(size_t)row*DIM + col] += (acc[rr][cc][tt] + bv)*lv;
            }
        }
    }
}

// ---------------- fully-MFMA fused talking-heads LSA attention (R4 version) ----
// block = (batch, 16-row i-tile), 512 threads / 8 waves.
#define SLAB    4488
#define IST     280
#define KV_OFF  53856
#define ROWP    200
#define Q_OFF   66656
#define PRE_OFF 69856
#define POST_OFF 70112
#define LTOT    71776

__global__ __launch_bounds__(512, 1) void attn_kernel(
        const f16_t* __restrict__ qb, const f16_t* __restrict__ kvb,
        const float* __restrict__ lsa, const float* __restrict__ pre,
        const float* __restrict__ post, bf16_t* __restrict__ ob){
    __shared__ ushort L[LTOT];
    int tid  = threadIdx.x;
    int lane = tid & 63, w = tid >> 6;
    int quad = lane >> 4, nr = lane & 15;
    int b  = blockIdx.x >> 4;
    int i0 = (blockIdx.x & 15) << 4;

    {
        uint* Z = (uint*)&L[KV_OFF];
        for (int k = tid; k < (LTOT - KV_OFF)/2; k += 512) Z[k] = 0;
    }
    __syncthreads();

    if (tid < 384){
        int e = tid*8, i = e/DIM, d = e%DIM, hh = d >> 4;
        float sc = lsa[hh];
        union { uint4 v; f16_t h[8]; } iv, ov;
        iv.v = *(const uint4*)(qb + (size_t)(b*SEQ + i0 + i)*DIM + d);
        #pragma unroll
        for (int u=0; u<8; u++) ov.h[u] = (f16_t)((float)iv.h[u]*sc);
        *(uint4*)&L[Q_OFF + i*ROWP + d] = ov.v;
    } else {
        for (int k = tid-384; k < 512; k += 128){
            int gg = (k & 255) >> 4, hh = k & 15;
            float v = 0.f;
            if (gg < 12 && hh < 12) v = (k < 256) ? pre[hh*12+gg] : post[hh*12+gg];
            L[(k < 256 ? PRE_OFF : (POST_OFF-256)) + k] = h2u((f16_t)v);
        }
    }
    auto stage_kv = [&](int c, int coloff){
        #pragma unroll
        for (int s = 0; s < 3; s++){
            int e = (tid + s*512)*8;
            int j = e/DIM, d = e%DIM;
            uint4 v = *(const uint4*)(kvb + (size_t)(b*SEQ + c*64 + j)*(2*DIM) + coloff + d);
            *(uint4*)&L[KV_OFF + j*ROWP + d] = v;
        }
    };
    stage_kv(0, 0);
    __syncthreads();

    int hbase = (w >> 2)*6;
    half4 qf[6];
    #pragma unroll
    for (int hh=0; hh<6; hh++)
        qf[hh] = *(const half4*)&L[Q_OFF + nr*ROWP + (hbase+hh)*16 + quad*4];
    half4 preTf  = *(const half4*)&L[PRE_OFF  + nr*16 + quad*4];
    half4 postTf = *(const half4*)&L[POST_OFF + nr*16 + quad*4];

    int jsl = w & 3;
    for (int c = 0; c < 4; c++){
        int j0g = c*64 + jsl*16;
        #pragma unroll
        for (int hh=0; hh<6; hh++){
            int h = hbase + hh;
            half4 bv = *(const half4*)&L[KV_OFF + (jsl*16 + nr)*ROWP + h*16 + quad*4];
            f32x4 a = __builtin_amdgcn_mfma_f32_16x16x16f16(qf[hh], bv, (f32x4){0,0,0,0}, 0,0,0);
            int jg = j0g + nr;
            #pragma unroll
            for (int t=0; t<4; t++){
                float v = a[t];
                if (i0 + quad*4 + t == jg) v = -1e-9f;
                L[h*SLAB + (quad*4+t)*IST + jg] = h2u((f16_t)v);
            }
        }
        __syncthreads();
        if (c < 3){ stage_kv(c+1, 0); __syncthreads(); }
    }

    for (int s = 0; s < 32; s++){
        int cb = s*8 + w;
        int i = cb >> 4, jb = cb & 15;
        int colbase = i*IST + jb*16 + nr;
        half4 bv;
        #pragma unroll
        for (int t=0; t<4; t++) bv[t] = u2h(L[(quad*4+t)*SLAB + colbase]);
        f32x4 cc = __builtin_amdgcn_mfma_f32_16x16x16f16(preTf, bv, (f32x4){0,0,0,0}, 0,0,0);
        if (quad < 3){
            #pragma unroll
            for (int t=0; t<4; t++) L[(quad*4+t)*SLAB + colbase] = h2u((f16_t)cc[t]);
        }
    }
    __syncthreads();

    for (int r = w; r < 192; r += 8){
        int g = r >> 4, i = r & 15;
        ushort* sp = &L[g*SLAB + i*IST];
        ushort4 uv = *(ushort4*)&sp[lane*4];
        float e0 = __expf((float)u2h(uv.x));
        float e1 = __expf((float)u2h(uv.y));
        float e2 = __expf((float)u2h(uv.z));
        float e3 = __expf((float)u2h(uv.w));
        float ssum = e0+e1+e2+e3;
        #pragma unroll
        for (int off=32; off; off>>=1) ssum += __shfl_xor(ssum, off, 64);
        float rin = 1.0f/ssum;
        uv.x = h2u((f16_t)(e0*rin)); uv.y = h2u((f16_t)(e1*rin));
        uv.z = h2u((f16_t)(e2*rin)); uv.w = h2u((f16_t)(e3*rin));
        *(ushort4*)&sp[lane*4] = uv;
    }
    __syncthreads();

    for (int s = 0; s < 32; s++){
        int cb = s*8 + w;
        int i = cb >> 4, jb = cb & 15;
        int colbase = i*IST + jb*16 + nr;
        half4 bv;
        #pragma unroll
        for (int t=0; t<4; t++) bv[t] = u2h(L[(quad*4+t)*SLAB + colbase]);
        f32x4 cc = __builtin_amdgcn_mfma_f32_16x16x16f16(postTf, bv, (f32x4){0,0,0,0}, 0,0,0);
        if (quad < 3){
            #pragma unroll
            for (int t=0; t<4; t++) L[(quad*4+t)*SLAB + colbase] = h2u((f16_t)cc[t]);
        }
    }
    __syncthreads();

    f32x4 oacc[2] = {{0,0,0,0},{0,0,0,0}};
    int g0 = w, g1 = (w < 4) ? 8 + w : -1;
    for (int c = 0; c < 4; c++){
        stage_kv(c, DIM);
        __syncthreads();
        #pragma unroll
        for (int sl = 0; sl < 2; sl++){
            int g = sl ? g1 : g0;
            if (g < 0) continue;
            #pragma unroll
            for (int ks = 0; ks < 4; ks++){
                int jl = ks*16 + quad*4;
                half4 av = *(const half4*)&L[g*SLAB + nr*IST + c*64 + jl];
                half4 bv;
                #pragma unroll
                for (int t=0; t<4; t++) bv[t] = u2h(L[KV_OFF + (jl+t)*ROWP + g*16 + nr]);
                oacc[sl] = __builtin_amdgcn_mfma_f32_16x16x16f16(av, bv, oacc[sl], 0,0,0);
            }
        }
        __syncthreads();
    }
    #pragma unroll
    for (int sl = 0; sl < 2; sl++){
        int g = sl ? g1 : g0;
        if (g < 0) continue;
        #pragma unroll
        for (int t=0; t<4; t++){
            int i = quad*4 + t;
            ob[(size_t)(b*SEQ + i0 + i)*DIM + g*16 + nr] = f2b(oacc[sl][t]);
        }
    }
}

extern "C" void kernel_launch(void* const* d_in, const int* in_sizes, int n_in,
                              void* d_out, int out_size, void* d_ws, size_t ws_size,
                              hipStream_t stream){
    const float* x    = (const float*)d_in[0];
    const float* ln1g = (const float*)d_in[1];
    const float* ln1b = (const float*)d_in[2];
    const float* Wq   = (const float*)d_in[3];
    const float* Wkv  = (const float*)d_in[4];
    const float* lsa  = (const float*)d_in[5];
    const float* pre  = (const float*)d_in[6];
    const float* post = (const float*)d_in[7];
    const float* Wo   = (const float*)d_in[8];
    const float* bo   = (const float*)d_in[9];
    const float* ls1  = (const float*)d_in[10];
    const float* ln2g = (const float*)d_in[11];
    const float* ln2b = (const float*)d_in[12];
    const float* W1   = (const float*)d_in[13];
    const float* b1   = (const float*)d_in[14];
    const float* W2   = (const float*)d_in[15];
    const float* b2   = (const float*)d_in[16];
    const float* ls2  = (const float*)d_in[17];
    float* xres = (float*)d_out;             // fp32 residual lives in d_out

    char* ws = (char*)d_ws;
    // union region: qb+kvb (QKV->attn) overlaps fb (W1->W2) — disjoint lifetimes
    f16_t*  qb  = (f16_t*)ws;
    f16_t*  kvb = (f16_t*)(ws + (size_t)ROWS*DIM*2);
    bf16_t* fb  = (bf16_t*)ws;
    char* p = ws + (size_t)ROWS*MLPD*2;
    bf16_t* ob  = (bf16_t*)p;  p += (size_t)ROWS*DIM*2;
    ushort* WqT  = (ushort*)p; p += (size_t)DEPTH*DIM*DIM*2;
    ushort* WkvT = (ushort*)p; p += (size_t)DEPTH*DIM*2*DIM*2;
    ushort* WoT  = (ushort*)p; p += (size_t)DEPTH*DIM*DIM*2;
    ushort* W1T  = (ushort*)p; p += (size_t)DEPTH*DIM*MLPD*2;
    ushort* W2T  = (ushort*)p; p += (size_t)DEPTH*MLPD*DIM*2;

    int ntot = ROWS*DIM;
    copy_kernel<<<ntot/256, 256, 0, stream>>>(x, xres, ntot);
    wt_kernel<<<dim3(3,3,6),  256, 0, stream>>>(Wq,  WqT,  DIM,  DIM);
    wt_kernel<<<dim3(3,6,6),  256, 0, stream>>>(Wkv, WkvT, DIM,  2*DIM);
    wt_kernel<<<dim3(3,3,6),  256, 0, stream>>>(Wo,  WoT,  DIM,  DIM);
    wt_kernel<<<dim3(3,12,6), 256, 0, stream>>>(W1,  W1T,  DIM,  MLPD);
    wt_kernel<<<dim3(12,3,6), 256, 0, stream>>>(W2,  W2T,  MLPD, DIM);
    for (int l = 0; l < DEPTH; l++){
        gemm_ln_kernel<0,3><<<dim3(128,3), 256, 0, stream>>>(xres,
                ln1g + l*DIM, ln1b + l*DIM,
                WqT + (size_t)l*DIM*DIM, WkvT + (size_t)l*DIM*2*DIM,
                nullptr, qb, kvb);
        attn_kernel<<<BATCH*(SEQ/16), 512, 0, stream>>>(qb, kvb, lsa + l*HEADS,
                pre + l*HEADS*HEADS, post + l*HEADS*HEADS, ob);
        gemm_a_kernel<1><<<dim3(128,3), 256, 0, stream>>>((const ushort*)ob,
                WoT + (size_t)l*DIM*DIM, bo + l*DIM, ls1 + l*DIM, xres);
        gemm_ln_kernel<1,4><<<dim3(128,3), 256, 0, stream>>>(xres,
                ln2g + l*DIM, ln2b + l*DIM,
                W1T + (size_t)l*DIM*MLPD, nullptr, b1 + l*MLPD, (f16_t*)fb, nullptr);
        gemm_a_kernel<4><<<dim3(128,3), 256, 0, stream>>>((const ushort*)fb,
                W2T + (size_t)l*MLPD*DIM, b2 + l*DIM, ls2 + l*DIM, xres);
    }
}

// Round 7
// 746.822 us; speedup vs baseline: 1.1548x; 1.0093x over previous
//
#include <hip/hip_runtime.h>
#include <hip/hip_bf16.h>

#define DEPTH   6
#define DIM     192
#define HEADS   12
#define DH      16
#define MLPD    768
#define SEQ     256
#define BATCH   32
#define ROWS    (BATCH*SEQ)   // 8192

typedef __attribute__((ext_vector_type(8))) short short8;
typedef __attribute__((ext_vector_type(4))) float f32x4;
typedef __attribute__((ext_vector_type(4))) _Float16 half4;
typedef __hip_bfloat16 bf16_t;
typedef _Float16 f16_t;

__device__ __forceinline__ bf16_t f2b(float v){ return __float2bfloat16(v); }
__device__ __forceinline__ ushort f2u(float v){
    union{ bf16_t b; ushort u; } w; w.b = __float2bfloat16(v); return w.u;
}
__device__ __forceinline__ f16_t u2h(ushort u){ union{ ushort u; f16_t h; } w; w.u = u; return w.h; }
__device__ __forceinline__ ushort h2u(f16_t h){ union{ ushort u; f16_t h; } w; w.h = h; return w.u; }

// async global->LDS, 16B per lane. LDS dest = wave-uniform base + lane*16B.
__device__ __forceinline__ void async16(ushort* lds, const ushort* gp){
    __builtin_amdgcn_global_load_lds(
        (const __attribute__((address_space(1))) uint*)gp,
        (__attribute__((address_space(3))) uint*)lds, 16, 0, 0);
}

// ---------------- residual init ----------------
__global__ void copy_kernel(const float* __restrict__ x, float* __restrict__ xr, int n){
    int i = blockIdx.x*256 + threadIdx.x;
    if (i < n) xr[i] = x[i];
}

// ---------------- weight transpose-convert: W[l][K][N] fp32 -> WT[l][N][K] bf16 ----
__global__ __launch_bounds__(256) void wt_kernel(const float* __restrict__ W,
        ushort* __restrict__ WT, int K, int N){
    __shared__ ushort T[64*72];
    int l = blockIdx.z;
    const float* src = W + ((size_t)l*K + blockIdx.x*64)*N + blockIdx.y*64;
    ushort* dst = WT + ((size_t)l*N + blockIdx.y*64)*K + blockIdx.x*64;
    int tid = threadIdx.x;
    int r = tid >> 2, c4 = (tid & 3)*16;
    #pragma unroll
    for (int u=0; u<4; u++){
        float4 v = *(const float4*)(src + (size_t)r*N + c4 + u*4);
        T[(c4+u*4+0)*72 + r] = f2u(v.x);
        T[(c4+u*4+1)*72 + r] = f2u(v.y);
        T[(c4+u*4+2)*72 + r] = f2u(v.z);
        T[(c4+u*4+3)*72 + r] = f2u(v.w);
    }
    __syncthreads();
    int n = tid >> 2, k8 = (tid & 3)*16;
    #pragma unroll
    for (int u=0; u<2; u++)
        *(uint4*)(dst + (size_t)n*K + k8 + u*8) = *(uint4*)&T[n*72 + k8 + u*8];
}

// ---------------- fused LN + GEMM, column-looping (K = DIM = 192) ----------------
// MODE 0: QKV -> out0 (f16 stride 192) for cols<192, else out1 (f16 stride 384)
// MODE 1: W1  -> +bias, exact GELU, bf16 to out0 (stride MLPD)
template<int MODE, int NT>
__global__ __launch_bounds__(256) void gemm_ln_kernel(
        const float* __restrict__ xres, const float* __restrict__ ln_g,
        const float* __restrict__ ln_b, const ushort* __restrict__ BT0,
        const ushort* __restrict__ BT1, const float* __restrict__ bias,
        f16_t* __restrict__ out0, f16_t* __restrict__ out1){
    __shared__ ushort As[64*200];      // LN'd A rows, stride 200 (2-way banks)
    __shared__ ushort Bs[2][6*2048];   // double-buffered N-tile (full K, packed 32k)
    int tid = threadIdx.x, lane = tid & 63, w = tid >> 6;
    int bm = blockIdx.x*64;
    int tile0 = blockIdx.y*NT;
    auto issueB = [&](int t, int buf){
        int bn = (tile0 + t)*64;
        const ushort* bt; int bnl;
        if (MODE == 0 && bn >= DIM){ bt = BT1; bnl = bn - DIM; }
        else { bt = BT0; bnl = bn; }
        const ushort* bp = bt + (size_t)(bnl + (tid>>2))*DIM + (tid&3)*8;
        #pragma unroll
        for (int c=0; c<6; c++)
            async16(&Bs[buf][c*2048 + tid*8], bp + c*32);
    };
    issueB(0, 0);
    // LN prologue: each block LNs its 64 rows ONCE
    float g0 = ln_g[lane], g1 = ln_g[lane+64], g2 = ln_g[lane+128];
    float e0 = ln_b[lane], e1 = ln_b[lane+64], e2 = ln_b[lane+128];
    for (int it = 0; it < 16; it++){
        int r = (w<<4) + it;
        const float* xr = xres + (size_t)(bm + r)*DIM;
        float v0 = xr[lane], v1 = xr[lane+64], v2 = xr[lane+128];
        float s = v0+v1+v2;
        #pragma unroll
        for (int off=32; off; off>>=1) s += __shfl_xor(s, off, 64);
        float m = s*(1.0f/192.0f);
        float d0=v0-m, d1=v1-m, d2=v2-m;
        float q = d0*d0+d1*d1+d2*d2;
        #pragma unroll
        for (int off=32; off; off>>=1) q += __shfl_xor(q, off, 64);
        float inv = rsqrtf(q*(1.0f/192.0f) + 1e-5f);
        ushort* dst = &As[r*200];
        dst[lane]     = f2u(d0*inv*g0 + e0);
        dst[lane+64]  = f2u(d1*inv*g1 + e1);
        dst[lane+128] = f2u(d2*inv*g2 + e2);
    }
    __syncthreads();   // drains tile-0 asyncs + As visible
    int wrow = w >> 1, wcol = w & 1;
    int quad = lane >> 4, mr = lane & 15;
    for (int t = 0; t < NT; t++){
        if (t+1 < NT) issueB(t+1, (t+1)&1);
        const ushort* B = Bs[t&1];
        f32x4 acc[2][2] = {};
        #pragma unroll
        for (int c = 0; c < 6; c++){
            short8 a0 = *(const short8*)&As[(wrow*32+mr)*200    + c*32 + quad*8];
            short8 a1 = *(const short8*)&As[(wrow*32+16+mr)*200 + c*32 + quad*8];
            short8 b0 = *(const short8*)&B[c*2048 + (wcol*32+mr)*32    + quad*8];
            short8 b1 = *(const short8*)&B[c*2048 + (wcol*32+16+mr)*32 + quad*8];
            acc[0][0] = __builtin_amdgcn_mfma_f32_16x16x32_bf16(a0, b0, acc[0][0], 0,0,0);
            acc[0][1] = __builtin_amdgcn_mfma_f32_16x16x32_bf16(a0, b1, acc[0][1], 0,0,0);
            acc[1][0] = __builtin_amdgcn_mfma_f32_16x16x32_bf16(a1, b0, acc[1][0], 0,0,0);
            acc[1][1] = __builtin_amdgcn_mfma_f32_16x16x32_bf16(a1, b1, acc[1][1], 0,0,0);
        }
        int bn = (tile0 + t)*64;
        #pragma unroll
        for (int rr=0; rr<2; rr++){
            #pragma unroll
            for (int cc=0; cc<2; cc++){
                int col = bn + wcol*32 + cc*16 + mr;
                if (MODE == 0){
                    f16_t* op; size_t st;
                    if (col < DIM){ op = out0 + col; st = DIM; }
                    else          { op = out1 + (col - DIM); st = 2*DIM; }
                    #pragma unroll
                    for (int tt=0; tt<4; tt++){
                        int row = bm + wrow*32 + rr*16 + quad*4 + tt;
                        op[(size_t)row*st] = (f16_t)acc[rr][cc][tt];
                    }
                } else {
                    float bv = bias[col];
                    #pragma unroll
                    for (int tt=0; tt<4; tt++){
                        int row = bm + wrow*32 + rr*16 + quad*4 + tt;
                        float z = acc[rr][cc][tt] + bv;
                        ((bf16_t*)out0)[(size_t)row*MLPD + col] =
                            f2b(0.5f*z*(1.0f + erff(z*0.70710678118654752f)));
                    }
                }
            }
        }
        __syncthreads();
    }
}

// ---------------- GEMM + residual epilogue: xres += (A@B^T + bias)*ls ----------
// ROUNDS rounds of 6 k-tiles (192 k per barrier-pair, 24 MFMAs/round)
template<int ROUNDS>
__global__ __launch_bounds__(256) void gemm_a_kernel(
        const ushort* __restrict__ A, const ushort* __restrict__ BT,
        const float* __restrict__ bias, const float* __restrict__ ls,
        float* __restrict__ xres){
    const int K = ROUNDS*192;
    __shared__ ushort As[6*2048];
    __shared__ ushort Bs[6*2048];
    int tid = threadIdx.x, lane = tid & 63, w = tid >> 6;
    int wrow = w >> 1, wcol = w & 1;
    int bm = blockIdx.x*64, bn = blockIdx.y*64;
    int quad = lane >> 4, mr = lane & 15;
    const ushort* ap = A  + (size_t)(bm + (tid>>2))*K + (tid&3)*8;
    const ushort* bp = BT + (size_t)(bn + (tid>>2))*K + (tid&3)*8;
    f32x4 acc[2][2] = {};
    for (int r = 0; r < ROUNDS; r++){
        #pragma unroll
        for (int c=0; c<6; c++){
            async16(&As[c*2048 + tid*8], ap + r*192 + c*32);
            async16(&Bs[c*2048 + tid*8], bp + r*192 + c*32);
        }
        __syncthreads();
        #pragma unroll
        for (int c=0; c<6; c++){
            short8 a0 = *(const short8*)&As[c*2048 + (wrow*32+mr)*32    + quad*8];
            short8 a1 = *(const short8*)&As[c*2048 + (wrow*32+16+mr)*32 + quad*8];
            short8 b0 = *(const short8*)&Bs[c*2048 + (wcol*32+mr)*32    + quad*8];
            short8 b1 = *(const short8*)&Bs[c*2048 + (wcol*32+16+mr)*32 + quad*8];
            acc[0][0] = __builtin_amdgcn_mfma_f32_16x16x32_bf16(a0, b0, acc[0][0], 0,0,0);
            acc[0][1] = __builtin_amdgcn_mfma_f32_16x16x32_bf16(a0, b1, acc[0][1], 0,0,0);
            acc[1][0] = __builtin_amdgcn_mfma_f32_16x16x32_bf16(a1, b0, acc[1][0], 0,0,0);
            acc[1][1] = __builtin_amdgcn_mfma_f32_16x16x32_bf16(a1, b1, acc[1][1], 0,0,0);
        }
        if (r+1 < ROUNDS) __syncthreads();
    }
    #pragma unroll
    for (int rr=0; rr<2; rr++){
        #pragma unroll
        for (int cc=0; cc<2; cc++){
            int col = bn + wcol*32 + cc*16 + mr;
            float bv = bias[col], lv = ls[col];
            #pragma unroll
            for (int tt=0; tt<4; tt++){
                int row = bm + wrow*32 + rr*16 + quad*4 + tt;
                xres[(size_t)row*DIM + col] += (acc[rr][cc][tt] + bv)*lv;
            }
        }
    }
}

// ---------------- fused talking-heads LSA attention (v3: reg-fused QK^T+mix_pre) ----
// block = (batch, 16-row i-tile), 512 threads / 8 waves.
// Wave w owns j-slice [w*32, w*32+32): computes logits for ALL 12 heads in regs
// (K-frags direct from global), applies diag + mix_pre in registers, writes the
// MIXED logits S'[g][i][j] to LDS. Softmax/mix_post/PV phases as before.
#define SLAB    4488
#define IST     280
#define KV_OFF  53856
#define ROWP    200
#define Q_OFF   66656
#define PRE_OFF 69856
#define POST_OFF 70112
#define LTOT    71776

__global__ __launch_bounds__(512, 1) void attn_kernel(
        const f16_t* __restrict__ qb, const f16_t* __restrict__ kvb,
        const float* __restrict__ lsa, const float* __restrict__ pre,
        const float* __restrict__ post, bf16_t* __restrict__ ob){
    __shared__ ushort L[LTOT];
    int tid  = threadIdx.x;
    int lane = tid & 63, w = tid >> 6;
    int quad = lane >> 4, nr = lane & 15;
    int b  = blockIdx.x >> 4;
    int i0 = (blockIdx.x & 15) << 4;

    // zero KV..end: P3's h=12..15 OOB reads must always see finite f16
    {
        uint* Z = (uint*)&L[KV_OFF];
        for (int k = tid; k < (LTOT - KV_OFF)/2; k += 512) Z[k] = 0;
    }
    __syncthreads();

    // stage Q (lsa folded) with tid<384; postT (transposed, zero-padded) with tid>=384
    if (tid < 384){
        int e = tid*8, i = e/DIM, d = e%DIM, hh = d >> 4;
        float sc = lsa[hh];
        union { uint4 v; f16_t h[8]; } iv, ov;
        iv.v = *(const uint4*)(qb + (size_t)(b*SEQ + i0 + i)*DIM + d);
        #pragma unroll
        for (int u=0; u<8; u++) ov.h[u] = (f16_t)((float)iv.h[u]*sc);
        *(uint4*)&L[Q_OFF + i*ROWP + d] = ov.v;
    } else {
        for (int k = tid-384; k < 256; k += 128){
            int gg = k >> 4, hh = k & 15;
            if (gg < 12 && hh < 12)
                L[POST_OFF + k] = h2u((f16_t)post[hh*12+gg]);
        }
    }
    auto stage_kv = [&](int c, int coloff){
        #pragma unroll
        for (int s = 0; s < 3; s++){
            int e = (tid + s*512)*8;
            int j = e/DIM, d = e%DIM;
            uint4 v = *(const uint4*)(kvb + (size_t)(b*SEQ + c*64 + j)*(2*DIM) + coloff + d);
            *(uint4*)&L[KV_OFF + j*ROWP + d] = v;
        }
    };
    __syncthreads();

    // Q frags for all 12 heads; postT frag
    half4 qf[12];
    #pragma unroll
    for (int h=0; h<12; h++)
        qf[h] = *(const half4*)&L[Q_OFF + nr*ROWP + h*16 + quad*4];
    half4 postTf = *(const half4*)&L[POST_OFF + nr*16 + quad*4];

    // ---- P1+P2 fused: QK^T (K direct from global) + diag + mix_pre in regs ----
    #pragma unroll
    for (int sub = 0; sub < 2; sub++){
        int jg = w*32 + sub*16 + nr;               // this lane's j column
        const f16_t* krow = kvb + (size_t)(b*SEQ + jg)*(2*DIM);
        f32x4 acc[12];
        #pragma unroll
        for (int h=0; h<12; h++){
            half4 bv = *(const half4*)(krow + h*DH + quad*4);
            acc[h] = __builtin_amdgcn_mfma_f32_16x16x16f16(qf[h], bv, (f32x4){0,0,0,0}, 0,0,0);
        }
        // diag: dots[i==j] = -1e-9 (before mix_pre), rows i = i0+quad*4+t
        #pragma unroll
        for (int t=0; t<4; t++){
            if (i0 + quad*4 + t == jg){
                #pragma unroll
                for (int h=0; h<12; h++) acc[h][t] = -1e-9f;
            }
        }
        // mix_pre in registers: S'[g] = sum_h acc[h] * pre[h][g]  (fp32)
        #pragma unroll
        for (int g=0; g<12; g++){
            float s0=0.f, s1=0.f, s2=0.f, s3=0.f;
            #pragma unroll
            for (int h=0; h<12; h++){
                float p = pre[h*12+g];
                s0 += acc[h][0]*p; s1 += acc[h][1]*p;
                s2 += acc[h][2]*p; s3 += acc[h][3]*p;
            }
            ushort* sp = &L[g*SLAB + jg];
            sp[(quad*4+0)*IST] = h2u((f16_t)s0);
            sp[(quad*4+1)*IST] = h2u((f16_t)s1);
            sp[(quad*4+2)*IST] = h2u((f16_t)s2);
            sp[(quad*4+3)*IST] = h2u((f16_t)s3);
        }
    }
    __syncthreads();

    // ---- softmax over j, vectorized rows ----
    for (int r = w; r < 192; r += 8){
        int g = r >> 4, i = r & 15;
        ushort* sp = &L[g*SLAB + i*IST];
        ushort4 uv = *(ushort4*)&sp[lane*4];
        float e0 = __expf((float)u2h(uv.x));
        float e1 = __expf((float)u2h(uv.y));
        float e2 = __expf((float)u2h(uv.z));
        float e3 = __expf((float)u2h(uv.w));
        float ssum = e0+e1+e2+e3;
        #pragma unroll
        for (int off=32; off; off>>=1) ssum += __shfl_xor(ssum, off, 64);
        float rin = 1.0f/ssum;
        uv.x = h2u((f16_t)(e0*rin)); uv.y = h2u((f16_t)(e1*rin));
        uv.z = h2u((f16_t)(e2*rin)); uv.w = h2u((f16_t)(e3*rin));
        *(ushort4*)&sp[lane*4] = uv;
    }
    __syncthreads();

    // ---- P3: mix_post via MFMA, in-place ----
    for (int s = 0; s < 32; s++){
        int cb = s*8 + w;
        int i = cb >> 4, jb = cb & 15;
        int colbase = i*IST + jb*16 + nr;
        half4 bv;
        #pragma unroll
        for (int t=0; t<4; t++) bv[t] = u2h(L[(quad*4+t)*SLAB + colbase]);
        f32x4 cc = __builtin_amdgcn_mfma_f32_16x16x16f16(postTf, bv, (f32x4){0,0,0,0}, 0,0,0);
        if (quad < 3){
            #pragma unroll
            for (int t=0; t<4; t++) L[(quad*4+t)*SLAB + colbase] = h2u((f16_t)cc[t]);
        }
    }
    __syncthreads();

    // ---- P4: O = P @ V via MFMA chains over j ----
    f32x4 oacc[2] = {{0,0,0,0},{0,0,0,0}};
    int g0 = w, g1 = (w < 4) ? 8 + w : -1;
    for (int c = 0; c < 4; c++){
        stage_kv(c, DIM);
        __syncthreads();
        #pragma unroll
        for (int sl = 0; sl < 2; sl++){
            int g = sl ? g1 : g0;
            if (g < 0) continue;
            #pragma unroll
            for (int ks = 0; ks < 4; ks++){
                int jl = ks*16 + quad*4;
                half4 av = *(const half4*)&L[g*SLAB + nr*IST + c*64 + jl];
                half4 bv;
                #pragma unroll
                for (int t=0; t<4; t++) bv[t] = u2h(L[KV_OFF + (jl+t)*ROWP + g*16 + nr]);
                oacc[sl] = __builtin_amdgcn_mfma_f32_16x16x16f16(av, bv, oacc[sl], 0,0,0);
            }
        }
        __syncthreads();
    }
    #pragma unroll
    for (int sl = 0; sl < 2; sl++){
        int g = sl ? g1 : g0;
        if (g < 0) continue;
        #pragma unroll
        for (int t=0; t<4; t++){
            int i = quad*4 + t;
            ob[(size_t)(b*SEQ + i0 + i)*DIM + g*16 + nr] = f2b(oacc[sl][t]);
        }
    }
}

extern "C" void kernel_launch(void* const* d_in, const int* in_sizes, int n_in,
                              void* d_out, int out_size, void* d_ws, size_t ws_size,
                              hipStream_t stream){
    const float* x    = (const float*)d_in[0];
    const float* ln1g = (const float*)d_in[1];
    const float* ln1b = (const float*)d_in[2];
    const float* Wq   = (const float*)d_in[3];
    const float* Wkv  = (const float*)d_in[4];
    const float* lsa  = (const float*)d_in[5];
    const float* pre  = (const float*)d_in[6];
    const float* post = (const float*)d_in[7];
    const float* Wo   = (const float*)d_in[8];
    const float* bo   = (const float*)d_in[9];
    const float* ls1  = (const float*)d_in[10];
    const float* ln2g = (const float*)d_in[11];
    const float* ln2b = (const float*)d_in[12];
    const float* W1   = (const float*)d_in[13];
    const float* b1   = (const float*)d_in[14];
    const float* W2   = (const float*)d_in[15];
    const float* b2   = (const float*)d_in[16];
    const float* ls2  = (const float*)d_in[17];
    float* xres = (float*)d_out;             // fp32 residual lives in d_out

    char* ws = (char*)d_ws;
    // union region: qb+kvb (QKV->attn) overlaps fb (W1->W2) — disjoint lifetimes
    f16_t*  qb  = (f16_t*)ws;
    f16_t*  kvb = (f16_t*)(ws + (size_t)ROWS*DIM*2);
    bf16_t* fb  = (bf16_t*)ws;
    char* p = ws + (size_t)ROWS*MLPD*2;
    bf16_t* ob  = (bf16_t*)p;  p += (size_t)ROWS*DIM*2;
    ushort* WqT  = (ushort*)p; p += (size_t)DEPTH*DIM*DIM*2;
    ushort* WkvT = (ushort*)p; p += (size_t)DEPTH*DIM*2*DIM*2;
    ushort* WoT  = (ushort*)p; p += (size_t)DEPTH*DIM*DIM*2;
    ushort* W1T  = (ushort*)p; p += (size_t)DEPTH*DIM*MLPD*2;
    ushort* W2T  = (ushort*)p; p += (size_t)DEPTH*MLPD*DIM*2;

    int ntot = ROWS*DIM;
    copy_kernel<<<ntot/256, 256, 0, stream>>>(x, xres, ntot);
    wt_kernel<<<dim3(3,3,6),  256, 0, stream>>>(Wq,  WqT,  DIM,  DIM);
    wt_kernel<<<dim3(3,6,6),  256, 0, stream>>>(Wkv, WkvT, DIM,  2*DIM);
    wt_kernel<<<dim3(3,3,6),  256, 0, stream>>>(Wo,  WoT,  DIM,  DIM);
    wt_kernel<<<dim3(3,12,6), 256, 0, stream>>>(W1,  W1T,  DIM,  MLPD);
    wt_kernel<<<dim3(12,3,6), 256, 0, stream>>>(W2,  W2T,  MLPD, DIM);
    for (int l = 0; l < DEPTH; l++){
        gemm_ln_kernel<0,3><<<dim3(128,3), 256, 0, stream>>>(xres,
                ln1g + l*DIM, ln1b + l*DIM,
                WqT + (size_t)l*DIM*DIM, WkvT + (size_t)l*DIM*2*DIM,
                nullptr, qb, kvb);
        attn_kernel<<<BATCH*(SEQ/16), 512, 0, stream>>>(qb, kvb, lsa + l*HEADS,
                pre + l*HEADS*HEADS, post + l*HEADS*HEADS, ob);
        gemm_a_kernel<1><<<dim3(128,3), 256, 0, stream>>>((const ushort*)ob,
                WoT + (size_t)l*DIM*DIM, bo + l*DIM, ls1 + l*DIM, xres);
        gemm_ln_kernel<1,4><<<dim3(128,3), 256, 0, stream>>>(xres,
                ln2g + l*DIM, ln2b + l*DIM,
                W1T + (size_t)l*DIM*MLPD, nullptr, b1 + l*MLPD, (f16_t*)fb, nullptr);
        gemm_a_kernel<4><<<dim3(128,3), 256, 0, stream>>>((const ushort*)fb,
                W2T + (size_t)l*MLPD*DIM, b2 + l*DIM, ls2 + l*DIM, xres);
    }
}